// Round 1
// baseline (790.383 us; speedup 1.0000x reference)
//
#include <hip/hip_runtime.h>
#include <hip/hip_bf16.h>

// Self-attention (SAGAN-style), B=4, C=256, N=4096, Cqk=16, fp32.
// Two-pass flash decomposition:
//   K1 proj_qk : q,k = Wq/Wk @ x + b         [B,16,N]
//   K2 proj_v  : vT[b][n][c] = Wv @ x + bv   (stored transposed for PV staging)
//   K3 stats   : sminv[b][m] = 1/sum_n exp(S[n,m])   (S = q^T k, no max needed:
//                s~N(0,16) so exp(s)<=~e^25, sums <1e15 -- far inside fp32 range)
//   K4 attn_pv : per m-block of 64, loop n-tiles of 64: recompute S tile,
//                P = exp(S)*sminv, O += V_tile @ P;  out = x + gamma*O.

constexpr int B_   = 4;
constexpr int C_   = 256;
constexpr int CQK  = 16;
constexpr int N_   = 4096;

// ---------------------------------------------------------------- K1: q,k proj
__global__ __launch_bounds__(256) void proj_qk_kernel(
    const float* __restrict__ x, const float* __restrict__ Wq, const float* __restrict__ bq,
    const float* __restrict__ Wk, const float* __restrict__ bk,
    float* __restrict__ q, float* __restrict__ k) {
  const int tid = threadIdx.x;
  const int b  = blockIdx.x >> 4;
  const int n  = ((blockIdx.x & 15) << 8) + tid;   // pixel index
  const float* xb = x + (size_t)b * C_ * N_ + n;
  float aq[CQK];
  float ak[CQK];
#pragma unroll
  for (int o = 0; o < CQK; ++o) { aq[o] = 0.f; ak[o] = 0.f; }
  for (int c = 0; c < C_; c += 4) {
    const float x0 = xb[(size_t)(c + 0) * N_];
    const float x1 = xb[(size_t)(c + 1) * N_];
    const float x2 = xb[(size_t)(c + 2) * N_];
    const float x3 = xb[(size_t)(c + 3) * N_];
#pragma unroll
    for (int o = 0; o < CQK; ++o) {
      const float* wq = &Wq[o * C_ + c];   // uniform address -> s_load
      const float* wk = &Wk[o * C_ + c];
      aq[o] += wq[0] * x0 + wq[1] * x1 + wq[2] * x2 + wq[3] * x3;
      ak[o] += wk[0] * x0 + wk[1] * x1 + wk[2] * x2 + wk[3] * x3;
    }
  }
#pragma unroll
  for (int o = 0; o < CQK; ++o) {
    q[((size_t)b * CQK + o) * N_ + n] = aq[o] + bq[o];
    k[((size_t)b * CQK + o) * N_ + n] = ak[o] + bk[o];
  }
}

// ---------------------------------------------------------------- K2: v proj (transposed out)
__global__ __launch_bounds__(256) void proj_v_kernel(
    const float* __restrict__ x, const float* __restrict__ Wv, const float* __restrict__ bv,
    float* __restrict__ vT) {
  __shared__ float Ws[32][68];   // Ws[cc][c], padded stride 68 (272B, 16B aligned)
  __shared__ float Xs[32][64];   // Xs[cc][n]
  const int tid = threadIdx.x;
  const int b  = blockIdx.z;
  const int c0 = blockIdx.y << 6;
  const int n0 = blockIdx.x << 6;
  const int cg = tid >> 4;       // 0..15 -> c quad
  const int ng = tid & 15;       // 0..15 -> n quad
  float acc[4][4];
#pragma unroll
  for (int i = 0; i < 4; ++i)
#pragma unroll
    for (int j = 0; j < 4; ++j) acc[i][j] = 0.f;

  for (int k0 = 0; k0 < C_; k0 += 32) {
    __syncthreads();
    {  // stage Wv tile transposed
      const int cr  = tid >> 2;          // 0..63  (c row)
      const int cc8 = (tid & 3) << 3;    // 0,8,16,24
      const float* wsrc = &Wv[(size_t)(c0 + cr) * C_ + k0 + cc8];
      float w[8];
      *(float4*)&w[0] = *(const float4*)&wsrc[0];
      *(float4*)&w[4] = *(const float4*)&wsrc[4];
#pragma unroll
      for (int i = 0; i < 8; ++i) Ws[cc8 + i][cr] = w[i];
    }
    {  // stage x tile (direct copy)
      const int r  = tid >> 3;           // 0..31
      const int c8 = (tid & 7) << 3;     // 0..56
      const float* xsrc = &x[((size_t)b * C_ + k0 + r) * N_ + n0 + c8];
      *(float4*)&Xs[r][c8]     = *(const float4*)&xsrc[0];
      *(float4*)&Xs[r][c8 + 4] = *(const float4*)&xsrc[4];
    }
    __syncthreads();
#pragma unroll
    for (int kk = 0; kk < 32; ++kk) {
      float w[4], xv[4];
      *(float4*)w  = *(const float4*)&Ws[kk][cg << 2];
      *(float4*)xv = *(const float4*)&Xs[kk][ng << 2];
#pragma unroll
      for (int i = 0; i < 4; ++i)
#pragma unroll
        for (int j = 0; j < 4; ++j) acc[i][j] += w[i] * xv[j];
    }
  }
  float bvv[4];
  *(float4*)bvv = *(const float4*)&bv[c0 + (cg << 2)];
#pragma unroll
  for (int j = 0; j < 4; ++j) {
    float r[4];
#pragma unroll
    for (int i = 0; i < 4; ++i) r[i] = acc[i][j] + bvv[i];
    *(float4*)&vT[((size_t)b * N_ + n0 + (ng << 2) + j) * C_ + c0 + (cg << 2)] = *(float4*)r;
  }
}

// ---------------------------------------------------------------- K3: softmax denominators
__global__ __launch_bounds__(256) void stats_kernel(
    const float* __restrict__ q, const float* __restrict__ k, float* __restrict__ sminv) {
  __shared__ float kbT[16][16];   // kbT[mm][c]
  __shared__ float red[4][16];
  const int tid = threadIdx.x;
  const int b  = blockIdx.y;
  const int m0 = blockIdx.x << 4;
  {
    const int c = tid >> 4, mm = tid & 15;
    kbT[mm][c] = k[((size_t)b * CQK + c) * N_ + m0 + mm];
  }
  __syncthreads();
  float smv[16];
#pragma unroll
  for (int mm = 0; mm < 16; ++mm) smv[mm] = 0.f;

  for (int it = 0; it < 4; ++it) {
    const int nn = (it << 10) + (tid << 2);   // 4 consecutive pixels per thread
    float4 qv[16];
#pragma unroll
    for (int c = 0; c < 16; ++c)
      qv[c] = *(const float4*)&q[((size_t)b * CQK + c) * N_ + nn];
#pragma unroll
    for (int mm = 0; mm < 16; ++mm) {
      float kr[16];
      *(float4*)&kr[0]  = *(const float4*)&kbT[mm][0];
      *(float4*)&kr[4]  = *(const float4*)&kbT[mm][4];
      *(float4*)&kr[8]  = *(const float4*)&kbT[mm][8];
      *(float4*)&kr[12] = *(const float4*)&kbT[mm][12];
      float s0 = 0.f, s1 = 0.f, s2 = 0.f, s3 = 0.f;
#pragma unroll
      for (int c = 0; c < 16; ++c) {
        s0 += qv[c].x * kr[c]; s1 += qv[c].y * kr[c];
        s2 += qv[c].z * kr[c]; s3 += qv[c].w * kr[c];
      }
      smv[mm] += (__expf(s0) + __expf(s1)) + (__expf(s2) + __expf(s3));
    }
  }
  // reduce across 64 lanes, then across 4 waves
#pragma unroll
  for (int mm = 0; mm < 16; ++mm) {
    float v = smv[mm];
#pragma unroll
    for (int off = 32; off > 0; off >>= 1) v += __shfl_xor(v, off, 64);
    smv[mm] = v;
  }
  const int wave = tid >> 6, lane = tid & 63;
  if (lane == 0) {
#pragma unroll
    for (int mm = 0; mm < 16; ++mm) red[wave][mm] = smv[mm];
  }
  __syncthreads();
  if (tid < 16) {
    const float tot = (red[0][tid] + red[1][tid]) + (red[2][tid] + red[3][tid]);
    sminv[(size_t)b * N_ + m0 + tid] = 1.0f / tot;
  }
}

// ---------------------------------------------------------------- K4: fused P + O = V*P
__global__ __launch_bounds__(256) void attn_pv_kernel(
    const float* __restrict__ x, const float* __restrict__ q, const float* __restrict__ k,
    const float* __restrict__ vT, const float* __restrict__ sminv,
    const float* __restrict__ gamma, float* __restrict__ out) {
  __shared__ float Vt[64][256];   // Vt[n][c]  (64 KB)
  __shared__ float P[64][64];     // P[n][m]   (16 KB)
  __shared__ float qtT[64][16];   // qtT[n][c] (4 KB)
  const int tid = threadIdx.x;
  const int b  = blockIdx.y;
  const int m0 = blockIdx.x << 6;
  const int lm = tid & 63;        // s-phase: m offset; PV: c-quad index
  const int wg = tid >> 6;        // 0..3

  float kreg[16];
#pragma unroll
  for (int c = 0; c < 16; ++c)
    kreg[c] = k[((size_t)b * CQK + c) * N_ + m0 + lm];
  const float sinv = sminv[(size_t)b * N_ + m0 + lm];
  const float g = gamma[0];

  float oacc[4][16];
#pragma unroll
  for (int i = 0; i < 4; ++i)
#pragma unroll
    for (int j = 0; j < 16; ++j) oacc[i][j] = 0.f;

  for (int t = 0; t < 64; ++t) {
    const int n0 = t << 6;
    __syncthreads();   // previous tile's P/Vt reads done before overwrite
    {  // stage q tile transposed: qtT[n][c]
      const int n  = tid >> 2;
      const int c4 = (tid & 3) << 2;
      float tmp[4];
#pragma unroll
      for (int i = 0; i < 4; ++i)
        tmp[i] = q[((size_t)b * CQK + c4 + i) * N_ + n0 + n];
      *(float4*)&qtT[n][c4] = *(float4*)tmp;
    }
    {  // stage V tile: fully coalesced global float4, contiguous LDS rows
      const float4* src = (const float4*)&vT[((size_t)b * N_ + n0) * C_];
#pragma unroll
      for (int qq = 0; qq < 16; ++qq) {
        const int f = (qq << 8) + tid;
        const float4 v = src[f];
        *(float4*)&Vt[f >> 6][(f & 63) << 2] = v;
      }
    }
    __syncthreads();
    // ---- score phase: P[n][m] = exp(S)*sminv  (each thread: its m, 16 n's)
#pragma unroll
    for (int j = 0; j < 16; ++j) {
      const int n = (wg << 4) + j;
      float kq[16];
      *(float4*)&kq[0]  = *(const float4*)&qtT[n][0];    // wave-uniform addr (broadcast)
      *(float4*)&kq[4]  = *(const float4*)&qtT[n][4];
      *(float4*)&kq[8]  = *(const float4*)&qtT[n][8];
      *(float4*)&kq[12] = *(const float4*)&qtT[n][12];
      float s = 0.f;
#pragma unroll
      for (int c = 0; c < 16; ++c) s += kq[c] * kreg[c];
      P[n][lm] = __expf(s) * sinv;
    }
    __syncthreads();
    // ---- PV phase: O[c,m] += sum_n Vt[n][c] * P[n][m]
#pragma unroll 4
    for (int kk = 0; kk < 64; ++kk) {
      float vv[4], pp[16];
      *(float4*)vv      = *(const float4*)&Vt[kk][lm << 2];
      *(float4*)&pp[0]  = *(const float4*)&P[kk][(wg << 4) + 0];
      *(float4*)&pp[4]  = *(const float4*)&P[kk][(wg << 4) + 4];
      *(float4*)&pp[8]  = *(const float4*)&P[kk][(wg << 4) + 8];
      *(float4*)&pp[12] = *(const float4*)&P[kk][(wg << 4) + 12];
#pragma unroll
      for (int i = 0; i < 4; ++i)
#pragma unroll
        for (int j = 0; j < 16; ++j) oacc[i][j] += vv[i] * pp[j];
    }
  }
  // ---- epilogue: out = x + gamma * O
#pragma unroll
  for (int i = 0; i < 4; ++i) {
    const size_t row = ((size_t)b * C_ + (lm << 2) + i) * N_ + m0 + (wg << 4);
#pragma unroll
    for (int j4 = 0; j4 < 4; ++j4) {
      float xa[4];
      *(float4*)xa = *(const float4*)&x[row + (j4 << 2)];
      float r[4];
#pragma unroll
      for (int e = 0; e < 4; ++e) r[e] = xa[e] + g * oacc[i][(j4 << 2) + e];
      *(float4*)&out[row + (j4 << 2)] = *(float4*)r;
    }
  }
}

// ---------------------------------------------------------------- launch
extern "C" void kernel_launch(void* const* d_in, const int* in_sizes, int n_in,
                              void* d_out, int out_size, void* d_ws, size_t ws_size,
                              hipStream_t stream) {
  const float* x     = (const float*)d_in[0];
  const float* Wq    = (const float*)d_in[1];
  const float* bq    = (const float*)d_in[2];
  const float* Wk    = (const float*)d_in[3];
  const float* bk    = (const float*)d_in[4];
  const float* Wv    = (const float*)d_in[5];
  const float* bv    = (const float*)d_in[6];
  const float* gamma = (const float*)d_in[7];
  float* out = (float*)d_out;

  float* qbuf = (float*)d_ws;                        // [B][16][N]
  float* kbuf = qbuf + (size_t)B_ * CQK * N_;        // [B][16][N]
  float* vT   = kbuf + (size_t)B_ * CQK * N_;        // [B][N][C]
  float* sinv = vT + (size_t)B_ * N_ * C_;           // [B][N]

  proj_qk_kernel<<<64, 256, 0, stream>>>(x, Wq, bq, Wk, bk, qbuf, kbuf);
  proj_v_kernel<<<dim3(64, 4, 4), 256, 0, stream>>>(x, Wv, bv, vT);
  stats_kernel<<<dim3(256, 4), 256, 0, stream>>>(qbuf, kbuf, sinv);
  attn_pv_kernel<<<dim3(64, 4), 256, 0, stream>>>(x, qbuf, kbuf, vT, sinv, gamma, out);
}

// Round 3
// 269.085 us; speedup vs baseline: 2.9373x; 2.9373x over previous
//
#include <hip/hip_runtime.h>
#include <hip/hip_bf16.h>

// SAGAN self-attention, B=4, C=256, N=4096, Cqk=16, fp32 I/O.
// Single-pass fused attention on MFMA (bf16):
//   K1 proj_qk : qT/kT[b][n][24] bf16 (16 valid ch, rows padded to 48 B)
//   K2 proj_v  : vbf[b][c][n] bf16
//   K3 attn    : per (b, 64-m block): loop 64 n-tiles:
//                  S = q^T k (MFMA, K=16 padded to 32), e = exp(S)
//                  den[m] += sum_n e ;  num[c,m] += V-tile @ e (MFMA)
//                out = x + gamma * num/den   (no max-subtraction: |S|<~30)

constexpr int B_  = 4;
constexpr int C_  = 256;
constexpr int CQK = 16;
constexpr int N_  = 4096;
constexpr int BN  = 64;
constexpr int NT  = N_ / BN;

typedef short   bf16x8  __attribute__((ext_vector_type(8)));
typedef short   short4v __attribute__((ext_vector_type(4)));
typedef unsigned short ushort8v __attribute__((ext_vector_type(8)));
typedef float   f32x4   __attribute__((ext_vector_type(4)));

#define GLOAD_LDS16(g, l) __builtin_amdgcn_global_load_lds( \
    (const __attribute__((address_space(1))) unsigned int*)(g), \
    (__attribute__((address_space(3))) unsigned int*)(l), 16, 0, 0)

__device__ __forceinline__ unsigned short f2bf(float f) {
  __hip_bfloat16 h = __float2bfloat16(f);
  return *reinterpret_cast<unsigned short*>(&h);
}

// ---------------------------------------------------------------- K1: q,k proj -> bf16 transposed
__global__ __launch_bounds__(256) void proj_qk_kernel(
    const float* __restrict__ x, const float* __restrict__ Wq, const float* __restrict__ bq,
    const float* __restrict__ Wk, const float* __restrict__ bk,
    unsigned short* __restrict__ qT, unsigned short* __restrict__ kT) {
  const int tid = threadIdx.x;
  const int b  = blockIdx.x >> 4;
  const int n  = ((blockIdx.x & 15) << 8) + tid;
  const float* xb = x + (size_t)b * C_ * N_ + n;
  float aq[CQK], ak[CQK];
#pragma unroll
  for (int o = 0; o < CQK; ++o) { aq[o] = 0.f; ak[o] = 0.f; }
  for (int c = 0; c < C_; c += 4) {
    const float x0 = xb[(size_t)(c + 0) * N_];
    const float x1 = xb[(size_t)(c + 1) * N_];
    const float x2 = xb[(size_t)(c + 2) * N_];
    const float x3 = xb[(size_t)(c + 3) * N_];
#pragma unroll
    for (int o = 0; o < CQK; ++o) {
      const float* wq = &Wq[o * C_ + c];   // wave-uniform -> scalar loads
      const float* wk = &Wk[o * C_ + c];
      aq[o] += wq[0] * x0 + wq[1] * x1 + wq[2] * x2 + wq[3] * x3;
      ak[o] += wk[0] * x0 + wk[1] * x1 + wk[2] * x2 + wk[3] * x3;
    }
  }
  ushort8v q0, q1, k0, k1;
#pragma unroll
  for (int o = 0; o < 8; ++o) {
    q0[o] = f2bf(aq[o] + bq[o]);       q1[o] = f2bf(aq[o + 8] + bq[o + 8]);
    k0[o] = f2bf(ak[o] + bk[o]);       k1[o] = f2bf(ak[o + 8] + bk[o + 8]);
  }
  const size_t base = ((size_t)b * N_ + n) * 24;   // rows padded to 24 elems (48 B)
  *(ushort8v*)&qT[base]     = q0;  *(ushort8v*)&qT[base + 8] = q1;
  *(ushort8v*)&kT[base]     = k0;  *(ushort8v*)&kT[base + 8] = k1;
}

// ---------------------------------------------------------------- K2: v proj -> vbf[b][c][n] bf16
__global__ __launch_bounds__(256) void proj_v_kernel(
    const float* __restrict__ x, const float* __restrict__ Wv, const float* __restrict__ bv,
    unsigned short* __restrict__ vbf) {
  __shared__ float Ws[32][68];
  __shared__ float Xs[32][64];
  const int tid = threadIdx.x;
  const int b  = blockIdx.z;
  const int c0 = blockIdx.y << 6;
  const int n0 = blockIdx.x << 6;
  const int cg = tid >> 4;
  const int ng = tid & 15;
  float acc[4][4];
#pragma unroll
  for (int i = 0; i < 4; ++i)
#pragma unroll
    for (int j = 0; j < 4; ++j) acc[i][j] = 0.f;

  for (int k0 = 0; k0 < C_; k0 += 32) {
    __syncthreads();
    {
      const int cr  = tid >> 2;
      const int cc8 = (tid & 3) << 3;
      const float* wsrc = &Wv[(size_t)(c0 + cr) * C_ + k0 + cc8];
      float w[8];
      *(float4*)&w[0] = *(const float4*)&wsrc[0];
      *(float4*)&w[4] = *(const float4*)&wsrc[4];
#pragma unroll
      for (int i = 0; i < 8; ++i) Ws[cc8 + i][cr] = w[i];
    }
    {
      const int r  = tid >> 3;
      const int c8 = (tid & 7) << 3;
      const float* xsrc = &x[((size_t)b * C_ + k0 + r) * N_ + n0 + c8];
      *(float4*)&Xs[r][c8]     = *(const float4*)&xsrc[0];
      *(float4*)&Xs[r][c8 + 4] = *(const float4*)&xsrc[4];
    }
    __syncthreads();
#pragma unroll
    for (int kk = 0; kk < 32; ++kk) {
      float w[4], xv[4];
      *(float4*)w  = *(const float4*)&Ws[kk][cg << 2];
      *(float4*)xv = *(const float4*)&Xs[kk][ng << 2];
#pragma unroll
      for (int i = 0; i < 4; ++i)
#pragma unroll
        for (int j = 0; j < 4; ++j) acc[i][j] += w[i] * xv[j];
    }
  }
  float bvv[4];
  *(float4*)bvv = *(const float4*)&bv[c0 + (cg << 2)];
#pragma unroll
  for (int i = 0; i < 4; ++i) {
    const int c = c0 + (cg << 2) + i;
    short4v r;
#pragma unroll
    for (int j = 0; j < 4; ++j) r[j] = (short)f2bf(acc[i][j] + bvv[i]);
    *(short4v*)&vbf[((size_t)b * C_ + c) * N_ + n0 + (ng << 2)] = r;
  }
}

// ---------------------------------------------------------------- K3: fused attention (MFMA)
__global__ __launch_bounds__(512) void attn_fused_kernel(
    const float* __restrict__ x, const unsigned short* __restrict__ qT,
    const unsigned short* __restrict__ kT, const unsigned short* __restrict__ vbf,
    const float* __restrict__ sgamma, float* __restrict__ out) {
  // LDS carve-up (47.6 KB): Vl swizzled [256][64] bf16 | Pl swizzled [64m][64n] bf16
  //                         qL [64][24] bf16 | kL [64][24] bf16 | denl[8][16] | zeros
  __shared__ __align__(16) char smem[47648];
  unsigned short* Vl = (unsigned short*)smem;            // 32768 B
  unsigned short* Pl = (unsigned short*)(smem + 32768);  //  8192 B
  unsigned short* qL = (unsigned short*)(smem + 40960);  //  3072 B
  unsigned short* kL = (unsigned short*)(smem + 44032);  //  3072 B
  float* denl        = (float*)(smem + 47104);           //   512 B
  float* zl          = (float*)(smem + 47616);           //    32 B zeros
  float* Tl          = (float*)smem;                     // epilogue overlay [128][64] f32

  const int tid = threadIdx.x;
  const int ln  = tid & 63, w = tid >> 6;
  const int g   = ln >> 4, li = ln & 15;
  const int wc  = w & 3,  wm = w >> 2;     // PV decomposition: c-quad, m-half
  const int fmS = w >> 1;                  // S-phase m-frag of this wave
  const int fnS0 = (w & 1) << 1;           // S-phase first n-frag

  // XCD-aware swizzle: 256 blocks, 8 XCDs -> XCD x gets logical [32x,32x+32)
  const int orig = blockIdx.x;
  const int swz  = ((orig & 7) << 5) + (orig >> 3);
  const int b  = swz >> 6;
  const int m0 = (swz & 63) << 6;

  if (tid < 8) zl[tid] = 0.f;

  const char* qbase = (const char*)qT + (size_t)b * N_ * 48;
  const char* kbase = (const char*)kT + (size_t)b * N_ * 48;
  const unsigned short* vb = vbf + (size_t)b * C_ * N_;

  // prologue: stage k rows [m0, m0+64) (3072 B, waves 0-2)
  if (w < 3) GLOAD_LDS16(kbase + (size_t)m0 * 48 + (w << 10) + (ln << 4), (char*)kL + (w << 10));
  __syncthreads();

  // persistent k B-fragment: col m = fmS*16+li, k-ch = g*8+e (g>=2 -> zeros)
  bf16x8 kfrag;
  {
    const char* addr = (g < 2) ? ((const char*)kL + (size_t)(fmS * 16 + li) * 48 + (g << 4))
                               : (const char*)zl;
    kfrag = *(const bf16x8*)addr;
  }

  f32x4 oacc[4][2];
#pragma unroll
  for (int cf = 0; cf < 4; ++cf)
#pragma unroll
    for (int mf = 0; mf < 2; ++mf) oacc[cf][mf] = (f32x4){0.f, 0.f, 0.f, 0.f};
  float den_part = 0.f;

  // V staging geometry: physical 16B slot (c,p) holds logical n-slot s = p^(c&7)
  const int cV = (w << 3) + (ln >> 3);        // row within 64-row group
  const int sV = (ln & 7) ^ (ln >> 3);        // pre-swizzled logical slot

  for (int t = 0; t < NT; ++t) {
    const int n0 = t << 6;
    __syncthreads();                           // prev tile's LDS reads complete
    if (w < 3) GLOAD_LDS16(qbase + (size_t)n0 * 48 + (w << 10) + (ln << 4), (char*)qL + (w << 10));
#pragma unroll
    for (int it = 0; it < 4; ++it) {
      const char* src = (const char*)vb + (((size_t)(it * 64 + cV)) * N_ + n0 + sV * 8) * 2;
      GLOAD_LDS16(src, (char*)Vl + it * 8192 + (w << 10));
    }
    __syncthreads();                           // stage visible (vmcnt drained by barrier)

    // ---- S phase: this wave computes S-frags (fnS0, fmS), (fnS0+1, fmS)
#pragma unroll
    for (int j = 0; j < 2; ++j) {
      const int fn = fnS0 + j;
      const char* aaddr = (g < 2) ? ((const char*)qL + (size_t)(fn * 16 + li) * 48 + (g << 4))
                                  : (const char*)zl;
      bf16x8 afrag = *(const bf16x8*)aaddr;
      f32x4 s = (f32x4){0.f, 0.f, 0.f, 0.f};
      s = __builtin_amdgcn_mfma_f32_16x16x32_bf16(afrag, kfrag, s, 0, 0, 0);
      // lane holds S[n = fn*16+4g+r][m = fmS*16+li]
      const float e0 = __expf(s[0]), e1 = __expf(s[1]), e2 = __expf(s[2]), e3 = __expf(s[3]);
      den_part += (e0 + e1) + (e2 + e3);
      short4v pk;
      pk[0] = (short)f2bf(e0); pk[1] = (short)f2bf(e1);
      pk[2] = (short)f2bf(e2); pk[3] = (short)f2bf(e3);
      const int mrow = fmS * 16 + li;
      const int boff = ((fn << 5) + (g << 3)) ^ ((mrow & 7) << 4);   // 8B-block swizzle
      *(short4v*)((char*)Pl + mrow * 128 + boff) = pk;
    }
    __syncthreads();                           // P complete

    // ---- PV phase: oacc[cf][mf] += V[c,n] @ P[n,m]
#pragma unroll
    for (int ks = 0; ks < 2; ++ks) {
      bf16x8 bfr[2];
#pragma unroll
      for (int mf = 0; mf < 2; ++mf) {
        const int mrow = wm * 32 + mf * 16 + li;
        const int off  = ((ks << 6) + (g << 4)) ^ ((mrow & 7) << 4);
        bfr[mf] = *(const bf16x8*)((const char*)Pl + mrow * 128 + off);
      }
#pragma unroll
      for (int cf = 0; cf < 4; ++cf) {
        const int crow = wc * 64 + cf * 16 + li;
        const int slot = ((ks << 2) + g) ^ (crow & 7);
        bf16x8 afr = *(const bf16x8*)((const char*)Vl + crow * 128 + (slot << 4));
#pragma unroll
        for (int mf = 0; mf < 2; ++mf)
          oacc[cf][mf] = __builtin_amdgcn_mfma_f32_16x16x32_bf16(afr, bfr[mf], oacc[cf][mf], 0, 0, 0);
      }
    }
  }

  // ---- den finalize: reduce over g (lanes same li, different g), then cross-wave
  float d = den_part;
  d += __shfl_xor(d, 16, 64);
  d += __shfl_xor(d, 32, 64);
  if (ln < 16) denl[w * 16 + li] = d;
  __syncthreads();                             // also: all PV LDS reads done

  const float gam = sgamma[0];
  float rden[2];
#pragma unroll
  for (int mf = 0; mf < 2; ++mf) {
    const int fm = wm * 2 + mf;                // global m-frag of this lane's m
    rden[mf] = 1.f / (denl[(fm * 2) * 16 + li] + denl[(fm * 2 + 1) * 16 + li]);
  }

  // ---- epilogue: LDS transpose (overlay on Vl) -> coalesced out = x + gamma*num/den
#pragma unroll
  for (int h = 0; h < 2; ++h) {
    __syncthreads();                           // Tl region free
    if ((wc >> 1) == h) {
#pragma unroll
      for (int cf = 0; cf < 4; ++cf) {
        const int cl = ((wc & 1) << 6) + cf * 16 + (g << 2);
#pragma unroll
        for (int mf = 0; mf < 2; ++mf) {
          const int ml = wm * 32 + mf * 16 + li;
#pragma unroll
          for (int r = 0; r < 4; ++r)
            Tl[(cl + r) * 64 + ml] = oacc[cf][mf][r] * rden[mf];
        }
      }
    }
    __syncthreads();
#pragma unroll
    for (int p = 0; p < 4; ++p) {
      const int clocal = (p << 5) + (tid >> 4);          // 0..127
      const int c  = (h << 7) + clocal;
      const int mo = (tid & 15) << 2;
      const size_t gi = ((size_t)b * C_ + c) * N_ + m0 + mo;
      const float4 xa = *(const float4*)&x[gi];
      const f32x4  ov = *(const f32x4*)&Tl[clocal * 64 + mo];
      float4 rr;
      rr.x = xa.x + gam * ov[0];
      rr.y = xa.y + gam * ov[1];
      rr.z = xa.z + gam * ov[2];
      rr.w = xa.w + gam * ov[3];
      *(float4*)&out[gi] = rr;
    }
  }
}

// ---------------------------------------------------------------- launch
extern "C" void kernel_launch(void* const* d_in, const int* in_sizes, int n_in,
                              void* d_out, int out_size, void* d_ws, size_t ws_size,
                              hipStream_t stream) {
  const float* x     = (const float*)d_in[0];
  const float* Wq    = (const float*)d_in[1];
  const float* bq    = (const float*)d_in[2];
  const float* Wk    = (const float*)d_in[3];
  const float* bk    = (const float*)d_in[4];
  const float* Wv    = (const float*)d_in[5];
  const float* bv    = (const float*)d_in[6];
  const float* gamma = (const float*)d_in[7];
  float* out = (float*)d_out;

  unsigned short* qTg = (unsigned short*)d_ws;              // [B][N][24] bf16 (48B rows)
  unsigned short* kTg = qTg + (size_t)B_ * N_ * 24;         // [B][N][24]
  unsigned short* vbf = kTg + (size_t)B_ * N_ * 24;         // [B][C][N]

  proj_qk_kernel<<<64, 256, 0, stream>>>(x, Wq, bq, Wk, bk, qTg, kTg);
  proj_v_kernel<<<dim3(64, 4, 4), 256, 0, stream>>>(x, Wv, bv, vbf);
  attn_fused_kernel<<<256, 512, 0, stream>>>(x, qTg, kTg, vbf, gamma, out);
}

// Round 4
// 161.879 us; speedup vs baseline: 4.8826x; 1.6623x over previous
//
#include <hip/hip_runtime.h>
#include <hip/hip_bf16.h>

// SAGAN self-attention, B=4, C=256, N=4096, Cqk=16, fp32 I/O.
//  K0 cast_w    : Wbf[288][256] bf16  (rows 0-15 Wq, 16-31 Wk, 32-287 Wv)
//  K1 proj_fused: Y = Wall @ x per batch (bf16 MFMA); emits qT/kT[b][n][24]
//                 (48B rows) and vbf[b][c][n]
//  K2 attn      : per (b, 64-m block), loop 64 n-tiles:
//                 S = q^T k (MFMA), e=exp(S); den += sum_n e; num += V @ e.
//                 V,q direct global->reg prefetch (L2-resident), only P in LDS.
//                 One raw s_barrier per tile (no vmcnt drain).
//                 out = x + gamma * num/den.

constexpr int B_  = 4;
constexpr int C_  = 256;
constexpr int N_  = 4096;
constexpr int NT  = 64;

typedef short   bf16x8  __attribute__((ext_vector_type(8)));
typedef short   short4v __attribute__((ext_vector_type(4)));
typedef unsigned short ushort8v __attribute__((ext_vector_type(8)));
typedef float   f32x4   __attribute__((ext_vector_type(4)));

__device__ __forceinline__ unsigned short f2bf(float f) {
  __hip_bfloat16 h = __float2bfloat16(f);
  return *reinterpret_cast<unsigned short*>(&h);
}

// ---------------------------------------------------------------- K0: W -> bf16
__global__ __launch_bounds__(256) void cast_w_kernel(
    const float* __restrict__ Wq, const float* __restrict__ Wk,
    const float* __restrict__ Wv, unsigned short* __restrict__ Wbf) {
  const int f = (blockIdx.x * 256 + threadIdx.x) * 8;   // < 73728; regions 8-aligned
  const float* src;
  if (f < 4096)      src = Wq + f;
  else if (f < 8192) src = Wk + (f - 4096);
  else               src = Wv + (f - 8192);
  f32x4 a = *(const f32x4*)src;
  f32x4 c = *(const f32x4*)(src + 4);
  ushort8v o;
#pragma unroll
  for (int e = 0; e < 4; ++e) { o[e] = f2bf(a[e]); o[4 + e] = f2bf(c[e]); }
  *(ushort8v*)&Wbf[f] = o;
}

// ---------------------------------------------------------------- K1: fused projections (MFMA)
__global__ __launch_bounds__(512) void proj_fused_kernel(
    const float* __restrict__ x, const unsigned short* __restrict__ Wbf,
    const float* __restrict__ bq, const float* __restrict__ bk,
    const float* __restrict__ bv,
    unsigned short* __restrict__ qT, unsigned short* __restrict__ kT,
    unsigned short* __restrict__ vbf) {
  __shared__ __align__(16) char xsm[32768];   // xT[64 n][256 k] bf16, 512B rows, XOR-swizzled
  const int tid = threadIdx.x;
  const int b  = blockIdx.y;
  const int n0 = blockIdx.x << 6;
  const int ln = tid & 63, w = tid >> 6;
  const int g  = ln >> 4, li = ln & 15;
  const float* xb = x + (size_t)b * C_ * N_ + n0;

  // ---- stage x tile with register 4x4 transpose, fp32 -> bf16
#pragma unroll
  for (int pass = 0; pass < 2; ++pass) {
    const int id = pass * 512 + tid;
    const int nq = id & 15, kq = id >> 4;      // k = 4*kq (0..252), n = 4*nq (0..60)
    const int k = kq << 2, nn = nq << 2;
    f32x4 r0 = *(const f32x4*)&xb[(size_t)(k + 0) * N_ + nn];
    f32x4 r1 = *(const f32x4*)&xb[(size_t)(k + 1) * N_ + nn];
    f32x4 r2 = *(const f32x4*)&xb[(size_t)(k + 2) * N_ + nn];
    f32x4 r3 = *(const f32x4*)&xb[(size_t)(k + 3) * N_ + nn];
#pragma unroll
    for (int j = 0; j < 4; ++j) {
      short4v p;
      p[0] = (short)f2bf(r0[j]); p[1] = (short)f2bf(r1[j]);
      p[2] = (short)f2bf(r2[j]); p[3] = (short)f2bf(r3[j]);
      const int row = nn + j;
      const int boff = row * 512 + (((k >> 3) ^ (row & 7)) << 4) + ((k & 7) << 1);
      *(short4v*)(xsm + boff) = p;
    }
  }
  __syncthreads();

  // ---- MFMA: wave w owns m-frags {2w, 2w+1} (+ {16+w} for w<2)
  const int nmf = (w < 2) ? 3 : 2;
  const int mfs0 = 2 * w, mfs1 = 2 * w + 1, mfs2 = 16 + w;
  f32x4 acc[3][4];
#pragma unroll
  for (int mi = 0; mi < 3; ++mi)
#pragma unroll
    for (int nf = 0; nf < 4; ++nf) acc[mi][nf] = (f32x4){0.f, 0.f, 0.f, 0.f};

  const char* wb = (const char*)Wbf;
#pragma unroll
  for (int kk = 0; kk < 8; ++kk) {
    bf16x8 bx[4];
#pragma unroll
    for (int nf = 0; nf < 4; ++nf) {
      const int row = nf * 16 + li;
      bx[nf] = *(const bf16x8*)(xsm + row * 512 + ((((kk << 2) + g) ^ (li & 7)) << 4));
    }
#pragma unroll
    for (int mi = 0; mi < 3; ++mi) {
      if (mi < nmf) {
        const int mf = (mi == 0) ? mfs0 : (mi == 1 ? mfs1 : mfs2);
        bf16x8 af = *(const bf16x8*)(wb + (size_t)(mf * 16 + li) * 512 + kk * 64 + g * 16);
#pragma unroll
        for (int nf = 0; nf < 4; ++nf)
          acc[mi][nf] = __builtin_amdgcn_mfma_f32_16x16x32_bf16(af, bx[nf], acc[mi][nf], 0, 0, 0);
      }
    }
  }

  // ---- epilogue: bias + store (no barrier needed; LDS dead)
#pragma unroll
  for (int mi = 0; mi < 3; ++mi) {
    if (mi < nmf) {
      const int mf = (mi == 0) ? mfs0 : (mi == 1 ? mfs1 : mfs2);
      f32x4 bb;
      if (mf == 0)      bb = *(const f32x4*)&bq[4 * g];
      else if (mf == 1) bb = *(const f32x4*)&bk[4 * g];
      else              bb = *(const f32x4*)&bv[(mf - 2) * 16 + 4 * g];
      if (mf >= 2) {
        const int c = (mf - 2) * 16 + 4 * g;
        unsigned short* vout = vbf + ((size_t)b * C_ + c) * N_ + n0;
#pragma unroll
        for (int r = 0; r < 4; ++r)
#pragma unroll
          for (int nf = 0; nf < 4; ++nf)
            vout[(size_t)r * N_ + nf * 16 + li] = f2bf(acc[mi][nf][r] + bb[r]);
      } else {
        unsigned short* o = (mf == 0 ? qT : kT) + ((size_t)b * N_ + n0) * 24 + 4 * g;
#pragma unroll
        for (int nf = 0; nf < 4; ++nf)
#pragma unroll
          for (int r = 0; r < 4; ++r)
            o[(size_t)(nf * 16 + li) * 24 + r] = f2bf(acc[mi][nf][r] + bb[r]);
      }
    }
  }
}

// ---------------------------------------------------------------- K2: fused attention
__global__ __launch_bounds__(512) void attn_fused_kernel(
    const float* __restrict__ x, const unsigned short* __restrict__ qT,
    const unsigned short* __restrict__ kT, const unsigned short* __restrict__ vbf,
    const float* __restrict__ sgamma, float* __restrict__ out) {
  // LDS: Pl0[64m][128B] | Pl1 | (epilogue overlay Tl[128][64] f32) | denl
  __shared__ __align__(16) char smem[33312];
  char* Pl0 = smem;
  char* Pl1 = smem + 8192;
  float* Tl   = (float*)smem;
  float* denl = (float*)(smem + 32768);

  const int tid = threadIdx.x;
  const int ln = tid & 63, w = tid >> 6;
  const int g  = ln >> 4, li = ln & 15;
  const int fmS  = w >> 1;            // S-phase m-frag
  const int fnS0 = (w & 1) << 1;      // S-phase first n-frag

  // XCD swizzle: blocks on XCD x -> logical [32x, 32x+32) (V-batch stays in one L2 pair)
  const int orig = blockIdx.x;
  const int swz  = ((orig & 7) << 5) + (orig >> 3);
  const int b  = swz >> 6;
  const int m0 = (swz & 63) << 6;

  const char* qbase = (const char*)qT + (size_t)b * N_ * 48;
  const char* kbase = (const char*)kT + (size_t)b * N_ * 48;
  const char* vb    = (const char*)vbf + (size_t)b * C_ * N_ * 2;

  const bf16x8 Z8 = (bf16x8){0, 0, 0, 0, 0, 0, 0, 0};

  // persistent k B-fragment (col m = fmS*16+li, ch = g*8+e; g>=2 zero-pad)
  const bf16x8 kfrag = (g < 2)
      ? *(const bf16x8*)(kbase + (size_t)(m0 + fmS * 16 + li) * 48 + g * 16) : Z8;

  // per-lane base pointers
  const char* qp0 = qbase + (size_t)(fnS0 * 16 + li) * 48 + g * 16;   // + t*3072 (+768 j=1)
  const char* vp0 = vb + (size_t)(w * 32 + li) * (N_ * 2) + g * 16;   // + cf2*16*N*2 + ks*64 + t*128

  f32x4 oacc[2][4];
#pragma unroll
  for (int c2 = 0; c2 < 2; ++c2)
#pragma unroll
    for (int mf = 0; mf < 4; ++mf) oacc[c2][mf] = (f32x4){0.f, 0.f, 0.f, 0.f};
  float den_part = 0.f;

  bf16x8 qA0, qA1, qB0, qB1;
  bf16x8 vA[2][2], vB[2][2];

  // prologue: issue t=0 loads
  qA0 = (g < 2) ? *(const bf16x8*)(qp0) : Z8;
  qA1 = (g < 2) ? *(const bf16x8*)(qp0 + 768) : Z8;
#pragma unroll
  for (int c2 = 0; c2 < 2; ++c2)
#pragma unroll
    for (int ks = 0; ks < 2; ++ks)
      vA[c2][ks] = *(const bf16x8*)(vp0 + (size_t)c2 * (16 * N_ * 2) + ks * 64);

#define TILE(CQ0, CQ1, CV, NQ0, NQ1, NV, PBUF, T) do {                               \
    const size_t tnb = (size_t)(((T) + 1) & 63);                                     \
    NQ0 = (g < 2) ? *(const bf16x8*)(qp0 + tnb * 3072) : Z8;                         \
    NQ1 = (g < 2) ? *(const bf16x8*)(qp0 + tnb * 3072 + 768) : Z8;                   \
    _Pragma("unroll")                                                                \
    for (int c2 = 0; c2 < 2; ++c2)                                                   \
      _Pragma("unroll")                                                              \
      for (int ks = 0; ks < 2; ++ks)                                                 \
        NV[c2][ks] = *(const bf16x8*)(vp0 + tnb * 128 +                              \
                                      (size_t)c2 * (16 * N_ * 2) + ks * 64);         \
    { /* S phase: frags (fnS0, fmS), (fnS0+1, fmS) */                                \
      const int mrow = fmS * 16 + li;                                                \
      f32x4 s0 = (f32x4){0.f, 0.f, 0.f, 0.f};                                        \
      s0 = __builtin_amdgcn_mfma_f32_16x16x32_bf16(CQ0, kfrag, s0, 0, 0, 0);         \
      float e0 = __expf(s0[0]), e1 = __expf(s0[1]);                                  \
      float e2 = __expf(s0[2]), e3 = __expf(s0[3]);                                  \
      den_part += (e0 + e1) + (e2 + e3);                                             \
      short4v pk0;                                                                   \
      pk0[0] = (short)f2bf(e0); pk0[1] = (short)f2bf(e1);                            \
      pk0[2] = (short)f2bf(e2); pk0[3] = (short)f2bf(e3);                            \
      *(short4v*)((PBUF) + mrow * 128 +                                              \
                  (((fnS0 << 5) + (g << 3)) ^ ((mrow & 7) << 4))) = pk0;             \
      f32x4 s1 = (f32x4){0.f, 0.f, 0.f, 0.f};                                        \
      s1 = __builtin_amdgcn_mfma_f32_16x16x32_bf16(CQ1, kfrag, s1, 0, 0, 0);         \
      float f0 = __expf(s1[0]), f1 = __expf(s1[1]);                                  \
      float f2v = __expf(s1[2]), f3 = __expf(s1[3]);                                 \
      den_part += (f0 + f1) + (f2v + f3);                                            \
      short4v pk1;                                                                   \
      pk1[0] = (short)f2bf(f0); pk1[1] = (short)f2bf(f1);                            \
      pk1[2] = (short)f2bf(f2v); pk1[3] = (short)f2bf(f3);                           \
      *(short4v*)((PBUF) + mrow * 128 +                                              \
                  ((((fnS0 + 1) << 5) + (g << 3)) ^ ((mrow & 7) << 4))) = pk1;       \
    }                                                                                \
    asm volatile("s_waitcnt lgkmcnt(0)" ::: "memory");                               \
    __builtin_amdgcn_sched_barrier(0);                                               \
    __builtin_amdgcn_s_barrier();                                                    \
    __builtin_amdgcn_sched_barrier(0);                                               \
    _Pragma("unroll")                                                                \
    for (int ks = 0; ks < 2; ++ks) {                                                 \
      bf16x8 bfr[4];                                                                 \
      _Pragma("unroll")                                                              \
      for (int mf = 0; mf < 4; ++mf) {                                               \
        const int mr = mf * 16 + li;                                                 \
        bfr[mf] = *(const bf16x8*)((PBUF) + mr * 128 +                               \
                                   (((ks << 6) + (g << 4)) ^ ((mr & 7) << 4)));      \
      }                                                                              \
      _Pragma("unroll")                                                              \
      for (int c2 = 0; c2 < 2; ++c2)                                                 \
        _Pragma("unroll")                                                            \
        for (int mf = 0; mf < 4; ++mf)                                               \
          oacc[c2][mf] = __builtin_amdgcn_mfma_f32_16x16x32_bf16(                    \
              CV[c2][ks], bfr[mf], oacc[c2][mf], 0, 0, 0);                           \
    }                                                                                \
  } while (0)

  for (int tt = 0; tt < NT / 2; ++tt) {
    TILE(qA0, qA1, vA, qB0, qB1, vB, Pl0, 2 * tt);
    TILE(qB0, qB1, vB, qA0, qA1, vA, Pl1, 2 * tt + 1);
  }
#undef TILE

  // ---- den reduce + epilogue
  float d = den_part;
  d += __shfl_xor(d, 16, 64);
  d += __shfl_xor(d, 32, 64);
  if (ln < 16) denl[w * 16 + li] = d;
  __syncthreads();                              // all waves past loop; denl visible

  float rden[4];
#pragma unroll
  for (int mf = 0; mf < 4; ++mf)
    rden[mf] = 1.f / (denl[(2 * mf) * 16 + li] + denl[(2 * mf + 1) * 16 + li]);
  const float gam = sgamma[0];

#pragma unroll
  for (int h = 0; h < 2; ++h) {
    __syncthreads();                            // Tl region free
    if ((w >> 2) == h) {
#pragma unroll
      for (int c2 = 0; c2 < 2; ++c2)
#pragma unroll
        for (int mf = 0; mf < 4; ++mf)
#pragma unroll
          for (int r = 0; r < 4; ++r)
            Tl[((w & 3) * 32 + c2 * 16 + 4 * g + r) * 64 + mf * 16 + li] =
                oacc[c2][mf][r] * rden[mf];
    }
    __syncthreads();
#pragma unroll
    for (int p = 0; p < 4; ++p) {
      const int clocal = (p << 5) + (tid >> 4);
      const int c  = (h << 7) + clocal;
      const int mo = (tid & 15) << 2;
      const size_t gi = ((size_t)b * C_ + c) * N_ + m0 + mo;
      const float4 xa = *(const float4*)&x[gi];
      const f32x4  ov = *(const f32x4*)&Tl[clocal * 64 + mo];
      float4 rr;
      rr.x = xa.x + gam * ov[0];
      rr.y = xa.y + gam * ov[1];
      rr.z = xa.z + gam * ov[2];
      rr.w = xa.w + gam * ov[3];
      *(float4*)&out[gi] = rr;
    }
  }
}

// ---------------------------------------------------------------- launch
extern "C" void kernel_launch(void* const* d_in, const int* in_sizes, int n_in,
                              void* d_out, int out_size, void* d_ws, size_t ws_size,
                              hipStream_t stream) {
  const float* x     = (const float*)d_in[0];
  const float* Wq    = (const float*)d_in[1];
  const float* bq    = (const float*)d_in[2];
  const float* Wk    = (const float*)d_in[3];
  const float* bk    = (const float*)d_in[4];
  const float* Wv    = (const float*)d_in[5];
  const float* bv    = (const float*)d_in[6];
  const float* gamma = (const float*)d_in[7];
  float* out = (float*)d_out;

  unsigned short* qTg = (unsigned short*)d_ws;              // [B][N][24] (48B rows)
  unsigned short* kTg = qTg + (size_t)B_ * N_ * 24;         // [B][N][24]
  unsigned short* vbf = kTg + (size_t)B_ * N_ * 24;         // [B][C][N]
  unsigned short* Wbf = vbf + (size_t)B_ * C_ * N_;         // [288][256]

  cast_w_kernel<<<36, 256, 0, stream>>>(Wq, Wk, Wv, Wbf);
  proj_fused_kernel<<<dim3(64, 4), 512, 0, stream>>>(x, Wbf, bq, bk, bv, qTg, kTg, vbf);
  attn_fused_kernel<<<256, 512, 0, stream>>>(x, qTg, kTg, vbf, gamma, out);
}